// Round 15
// baseline (212.296 us; speedup 1.0000x reference)
//
#include <hip/hip_runtime.h>
#include <stdint.h>

// 3-layer binary net. L0 fused in main (bits via ballot, expand to i8 LDS).
// L1 = i8 MFMA GEMM (matches = 1024 - popx - popm + 2*s01, thresholds folded
// into carr). L2 + epilogue fused. B (M01 i8) lives in fragment-order ws (1MB,
// L2-hot, shared by all blocks).
// ws: cA 256K | cB 256K | M2p 3KB | carr 4KB | Bf 1MB
#define WS_CA   0
#define WS_CB   262144
#define WS_M2P  524288
#define WS_CARR 527360
#define WS_BF   532480

typedef int v4i  __attribute__((ext_vector_type(4)));
typedef int v16i __attribute__((ext_vector_type(16)));

// 16 bits -> 16 bytes (0/1), byte e = bit e (LSB-first)
__device__ __forceinline__ v4i expand16(unsigned h) {
  v4i a;
  a.x = (int)(__umul24(h & 15u,         0x00204081u) & 0x01010101u);
  a.y = (int)(__umul24((h >> 4) & 15u,  0x00204081u) & 0x01010101u);
  a.z = (int)(__umul24((h >> 8) & 15u,  0x00204081u) & 0x01010101u);
  a.w = (int)(__umul24((h >> 12) & 15u, 0x00204081u) & 0x01010101u);
  return a;
}

// ---- mask upload-format sniffing (bool arrays may arrive as u8, i32, or f32) ----
__device__ inline int detect_mode(const unsigned char* p) {
  unsigned nonalign = 0;
  for (int i = 0; i < 64; i++)
    if (i & 3) nonalign |= p[i];
  if (nonalign == 0) return 1;                 // int32 0/1
  bool f32ok = true;
  for (int e = 0; e < 16; e++) {
    const unsigned char* q = p + 4 * e;
    bool one  = (q[0] == 0 && q[1] == 0 && q[2] == 0x80 && q[3] == 0x3F);
    bool zero = (q[0] == 0 && q[1] == 0 && q[2] == 0 && q[3] == 0);
    if (!(one || zero)) { f32ok = false; break; }
  }
  return f32ok ? 2 : 0;
}

__device__ inline int maskbit(const unsigned char* p, int idx, int mode) {
  if (mode == 1) return ((const int*)p)[idx] & 1;
  if (mode == 2) return ((const float*)p)[idx] != 0.0f;
  return p[idx] & 1;
}

__global__ __launch_bounds__(256) void prep_kernel(
    const unsigned char* __restrict__ mask0, const int* __restrict__ thr0,
    const unsigned char* __restrict__ mask1, const unsigned char* __restrict__ mask2,
    signed char* __restrict__ cA, unsigned char* __restrict__ cB,
    unsigned char* __restrict__ Bf, unsigned* __restrict__ M2p) {
  __shared__ int smode;
  if (threadIdx.x == 0) smode = detect_mode(mask1);
  __syncthreads();
  int mode = smode;
  int gid = blockIdx.x * 256 + threadIdx.x;
  if (gid < 524288) {              // cA / cB tables for L0
    int which = gid >> 18;
    int idx = gid & 262143;
    int hw = idx >> 10;
    int o  = idx & 1023;
    int base = which ? 8 : 0;
    int cnt = 0;
#pragma unroll
    for (int i = 0; i < 8; i++) {
      int xb = (hw >> (7 - i)) & 1;                     // MSB-first bits
      int mb = maskbit(mask0, (base + i) * 1024 + o, mode);
      cnt += (xb == mb);
    }
    if (which) cB[idx] = (unsigned char)cnt;
    else       cA[idx] = (signed char)(cnt - thr0[o]);
    return;
  }
  int g1 = gid - 524288;
  if (g1 < 262144) {               // M01 -> Bf fragment layout (i8, MFMA B order)
    int o  = g1 & 1023;
    int kk = g1 >> 10;             // u32 chunk: feats 4kk..4kk+3
    unsigned u = 0;
#pragma unroll
    for (int j = 0; j < 4; j++)
      u |= (unsigned)maskbit(mask1, (4 * kk + j) * 1024 + o, mode) << (8 * j);
    // feat f=4kk: ks=kk>>3, g=(kk>>2)&1; frag = [oc32][ks][g][col][e]
    unsigned off = ((unsigned)(o >> 5) << 15) + ((unsigned)(kk >> 3) << 10) +
                   ((unsigned)((kk >> 2) & 1) << 9) + ((unsigned)(o & 31) << 4) +
                   ((unsigned)(kk & 3) << 2);
    *reinterpret_cast<unsigned*>(Bf + off) = u;
    return;
  }
  int g2 = g1 - 262144;
  if (g2 < 768) {                  // pack mask2: M2p[o][kw], LSB-first
    int kw = g2 / 24, o = g2 % 24;
    unsigned wv = 0;
    for (int b = 0; b < 32; b++)
      wv |= (unsigned)maskbit(mask2, (kw * 32 + b) * 24 + o, mode) << b;
    M2p[o * 32 + kw] = wv;
  }
}

// popm: column-sum of Bf (bytes 0/1 -> popc per u32 = byte sum). 1 wave per o.
__global__ __launch_bounds__(64) void popm_kernel(
    const unsigned char* __restrict__ Bf, const int* __restrict__ thr1,
    int* __restrict__ carr) {
  int o = blockIdx.x;
  int t = threadIdx.x;               // t = ks*2+g
  const uint4* p = reinterpret_cast<const uint4*>(
      Bf + ((unsigned)(o >> 5) << 15) + ((unsigned)(t >> 1) << 10) +
      ((unsigned)(t & 1) << 9) + ((unsigned)(o & 31) << 4));
  uint4 v = *p;
  int s = __popc(v.x) + __popc(v.y) + __popc(v.z) + __popc(v.w);
#pragma unroll
  for (int d = 32; d >= 1; d >>= 1) s += __shfl_down(s, d);
  if (t == 0) carr[o] = thr1[o] + s - 1024;
}

// Mega-main: block = 128 px x 1024 outs, 1024 threads (16 waves), grid 512.
// Phases: L0 bits (ballot) -> expand to 128KB i8 A-tile -> 2-pass MFMA
// (wave = 1 oc32 chunk x 4 row-tiles, B 2-deep prefetch from L2-hot Bf)
// -> threshold/ballot-pack -> fused L2 + epilogue.
__global__ __launch_bounds__(1024) void main_kernel(
    const signed char* __restrict__ cA, const unsigned char* __restrict__ cB,
    const unsigned char* __restrict__ Bf, const int* __restrict__ carr,
    const unsigned* __restrict__ M2p, const int* __restrict__ thr2,
    const float* __restrict__ image, float* __restrict__ out) {
  __shared__ v4i Ae4[8192];          // 128 KB [chunk c=2ks+g 0..63][row 0..127]
  __shared__ unsigned lbits[4224];   // 16.5 KB [row 0..127][wd 0..31] stride 33
  __shared__ unsigned lm2[768];      //  3 KB
  __shared__ int spopx[128];
  int t = threadIdx.x;
  int lane = t & 63;
  int wv = t >> 6;                   // wave 0..15
  int n0 = blockIdx.x << 7;
  int h = n0 >> 8;
  int w0 = n0 & 255;

  for (int r = t; r < 768; r += 1024) lm2[r] = M2p[r];
  if (t < 128) spopx[t] = 0;
  __syncthreads();

  // ---- L0a: bits via ballot (thread t owns feature o=t; loop over 128 rows)
  {
    int o = t;
    int av = (int)cA[h * 1024 + o];
    const unsigned char* cb = cB + (unsigned)w0 * 1024 + o;
#pragma unroll 1
    for (int r = 0; r < 128; r++) {
      bool bit = (av + (int)cb[(unsigned)r * 1024]) > 0;   // cA+cB > thr0
      unsigned long long bal = __ballot(bit);
      if (lane == 0) {
        lbits[r * 33 + wv * 2]     = (unsigned)bal;
        lbits[r * 33 + wv * 2 + 1] = (unsigned)(bal >> 32);
        atomicAdd(&spopx[r], __popcll(bal));
      }
    }
  }
  __syncthreads();

  // ---- L0b: expand bits -> i8 A-tile (writes lane->consecutive row: no conflict)
  {
    int r = t & 127;
    int c0 = (t >> 7) << 3;          // 8 chunks per thread
#pragma unroll
    for (int ci = 0; ci < 8; ci++) {
      int c = c0 + ci;               // halfword index 0..63 (= 2ks+g)
      unsigned word = lbits[r * 33 + (c >> 1)];
      unsigned hwv = (c & 1) ? (word >> 16) : (word & 0xFFFFu);
      Ae4[c * 128 + r] = expand16(hwv);
    }
  }
  __syncthreads();

  // ---- L1: MFMA. xbits overlays lbits (stride 33).
  unsigned* xbits = lbits;
  int g = lane >> 5;
  int col = lane & 31;

#pragma unroll 1
  for (int pass = 0; pass < 2; pass++) {
    int oc = (pass << 4) + wv;       // oc32 chunk 0..31
    const unsigned char* bp = Bf + ((unsigned)oc << 15) + (g << 9) + (col << 4);

    v16i acc0 = {0,0,0,0,0,0,0,0,0,0,0,0,0,0,0,0};
    v16i acc1 = acc0, acc2 = acc0, acc3 = acc0;

    v4i bA = *reinterpret_cast<const v4i*>(bp);
    v4i bB = *reinterpret_cast<const v4i*>(bp + 1024);
#pragma unroll 1
    for (int ks = 0; ks < 32; ks++) {
      v4i bu = bA;
      bA = bB;
      if (ks < 30) bB = *reinterpret_cast<const v4i*>(bp + (ks + 2) * 1024);
      int c = 2 * ks + g;
      v4i a0 = Ae4[c * 128 + col];
      v4i a1 = Ae4[c * 128 + 32 + col];
      v4i a2 = Ae4[c * 128 + 64 + col];
      v4i a3 = Ae4[c * 128 + 96 + col];
      acc0 = __builtin_amdgcn_mfma_i32_32x32x32_i8(a0, bu, acc0, 0, 0, 0);
      acc1 = __builtin_amdgcn_mfma_i32_32x32x32_i8(a1, bu, acc1, 0, 0, 0);
      acc2 = __builtin_amdgcn_mfma_i32_32x32x32_i8(a2, bu, acc2, 0, 0, 0);
      acc3 = __builtin_amdgcn_mfma_i32_32x32x32_i8(a3, bu, acc3, 0, 0, 0);
    }

    // threshold + ballot-pack into xbits
    int cv = carr[(oc << 5) + col];
#pragma unroll
    for (int rt = 0; rt < 4; rt++) {
      v16i av = (rt == 0) ? acc0 : (rt == 1) ? acc1 : (rt == 2) ? acc2 : acc3;
#pragma unroll
      for (int reg = 0; reg < 16; reg++) {
        int px_lo = (rt << 5) + (reg & 3) + ((reg >> 2) << 3);
        int px = px_lo + (g << 2);
        bool bit = (2 * av[reg]) > (cv + spopx[px]);
        unsigned long long bal = __ballot(bit);
        if (lane == 0) {
          xbits[px_lo * 33 + oc]       = (unsigned)bal;
          xbits[(px_lo + 4) * 33 + oc] = (unsigned)(bal >> 32);
        }
      }
    }
  }
  __syncthreads();

  // ---- fused layer-2 + epilogue (xbits stride 33; reads staggered by px)
  int px = t >> 3, sub = t & 7;
  if (sub < 3) {
    int c = sub;
    int n = n0 + px;
    int val = 0;
#pragma unroll
    for (int b = 0; b < 8; b++) {
      int o = c * 8 + b;
      unsigned acc2s = 0;
#pragma unroll
      for (int wi = 0; wi < 32; wi++) {
        int w = (wi + px) & 31;
        acc2s += __popc(xbits[px * 33 + w] ^ lm2[o * 32 + w]);
      }
      int bit = ((int)(1024u - acc2s)) > thr2[o];
      val |= bit << (7 - b);                            // MSB-first
    }
    out[c * 65536 + n] = (float)val;
    out[196608 + c * 65536 + n] = (float)val - image[c * 65536 + n];
  }
}

extern "C" void kernel_launch(void* const* d_in, const int* in_sizes, int n_in,
                              void* d_out, int out_size, void* d_ws, size_t ws_size,
                              hipStream_t stream) {
  const float*         image = (const float*)d_in[0];
  const unsigned char* mask0 = (const unsigned char*)d_in[1];
  const int*           thr0  = (const int*)d_in[2];
  const unsigned char* mask1 = (const unsigned char*)d_in[3];
  const int*           thr1  = (const int*)d_in[4];
  const unsigned char* mask2 = (const unsigned char*)d_in[5];
  const int*           thr2  = (const int*)d_in[6];
  char* ws = (char*)d_ws;
  signed char*    cA    = (signed char*)(ws + WS_CA);
  unsigned char*  cB    = (unsigned char*)(ws + WS_CB);
  unsigned*       M2p   = (unsigned*)(ws + WS_M2P);
  int*            carr  = (int*)(ws + WS_CARR);
  unsigned char*  Bf    = (unsigned char*)(ws + WS_BF);
  float* out = (float*)d_out;

  hipLaunchKernelGGL(prep_kernel, dim3(3075), dim3(256), 0, stream,
                     mask0, thr0, mask1, mask2, cA, cB, Bf, M2p);
  hipLaunchKernelGGL(popm_kernel, dim3(1024), dim3(64), 0, stream,
                     Bf, thr1, carr);
  hipLaunchKernelGGL(main_kernel, dim3(512), dim3(1024), 0, stream,
                     cA, cB, Bf, carr, M2p, thr2, image, out);
}

// Round 16
// 152.597 us; speedup vs baseline: 1.3912x; 1.3912x over previous
//
#include <hip/hip_runtime.h>
#include <stdint.h>

// 3-layer binary net, single fused main kernel (L0 ballot -> i8 expand ->
// i8 MFMA GEMM -> threshold -> L2 popcount -> epilogue).
// matches = 1024 - popx - popm + 2*(X01.M01^T); thr folded into carr.
// ws: cA 256K | cB 256K | M2p 3KB | carr 4KB | Bf 1MB (fragment-order i8, L2-hot)
#define WS_CA   0
#define WS_CB   262144
#define WS_M2P  524288
#define WS_CARR 527360
#define WS_BF   532480

typedef int v4i  __attribute__((ext_vector_type(4)));
typedef int v16i __attribute__((ext_vector_type(16)));

// 16 bits -> 16 bytes (0/1), byte e = bit e (LSB-first)
__device__ __forceinline__ v4i expand16(unsigned h) {
  v4i a;
  a.x = (int)(__umul24(h & 15u,         0x00204081u) & 0x01010101u);
  a.y = (int)(__umul24((h >> 4) & 15u,  0x00204081u) & 0x01010101u);
  a.z = (int)(__umul24((h >> 8) & 15u,  0x00204081u) & 0x01010101u);
  a.w = (int)(__umul24((h >> 12) & 15u, 0x00204081u) & 0x01010101u);
  return a;
}

// ---- mask upload-format sniffing (bool arrays may arrive as u8, i32, or f32) ----
__device__ inline int detect_mode(const unsigned char* p) {
  unsigned nonalign = 0;
  for (int i = 0; i < 64; i++)
    if (i & 3) nonalign |= p[i];
  if (nonalign == 0) return 1;                 // int32 0/1
  bool f32ok = true;
  for (int e = 0; e < 16; e++) {
    const unsigned char* q = p + 4 * e;
    bool one  = (q[0] == 0 && q[1] == 0 && q[2] == 0x80 && q[3] == 0x3F);
    bool zero = (q[0] == 0 && q[1] == 0 && q[2] == 0 && q[3] == 0);
    if (!(one || zero)) { f32ok = false; break; }
  }
  return f32ok ? 2 : 0;
}

__device__ inline int maskbit(const unsigned char* p, int idx, int mode) {
  if (mode == 1) return ((const int*)p)[idx] & 1;
  if (mode == 2) return ((const float*)p)[idx] != 0.0f;
  return p[idx] & 1;
}

__global__ __launch_bounds__(256) void prep_kernel(
    const unsigned char* __restrict__ mask0, const int* __restrict__ thr0,
    const unsigned char* __restrict__ mask1, const unsigned char* __restrict__ mask2,
    signed char* __restrict__ cA, unsigned char* __restrict__ cB,
    unsigned char* __restrict__ Bf, unsigned* __restrict__ M2p) {
  __shared__ int smode;
  if (threadIdx.x == 0) smode = detect_mode(mask1);
  __syncthreads();
  int mode = smode;
  int gid = blockIdx.x * 256 + threadIdx.x;
  if (gid < 524288) {              // cA / cB tables for L0
    int which = gid >> 18;
    int idx = gid & 262143;
    int hw = idx >> 10;
    int o  = idx & 1023;
    int base = which ? 8 : 0;
    int cnt = 0;
#pragma unroll
    for (int i = 0; i < 8; i++) {
      int xb = (hw >> (7 - i)) & 1;                     // MSB-first bits
      int mb = maskbit(mask0, (base + i) * 1024 + o, mode);
      cnt += (xb == mb);
    }
    if (which) cB[idx] = (unsigned char)cnt;
    else       cA[idx] = (signed char)(cnt - thr0[o]);
    return;
  }
  int g1 = gid - 524288;
  if (g1 < 262144) {               // M01 -> Bf fragment layout (i8, MFMA B order)
    int o  = g1 & 1023;
    int kk = g1 >> 10;             // u32 chunk: feats 4kk..4kk+3
    unsigned u = 0;
#pragma unroll
    for (int j = 0; j < 4; j++)
      u |= (unsigned)maskbit(mask1, (4 * kk + j) * 1024 + o, mode) << (8 * j);
    // feat f=4kk: ks=kk>>3, g=(kk>>2)&1; frag = [oc32][ks][g][col][e]
    unsigned off = ((unsigned)(o >> 5) << 15) + ((unsigned)(kk >> 3) << 10) +
                   ((unsigned)((kk >> 2) & 1) << 9) + ((unsigned)(o & 31) << 4) +
                   ((unsigned)(kk & 3) << 2);
    *reinterpret_cast<unsigned*>(Bf + off) = u;
    return;
  }
  int g2 = g1 - 262144;
  if (g2 < 768) {                  // pack mask2: M2p[o][kw], LSB-first
    int kw = g2 / 24, o = g2 % 24;
    unsigned wv = 0;
    for (int b = 0; b < 32; b++)
      wv |= (unsigned)maskbit(mask2, (kw * 32 + b) * 24 + o, mode) << b;
    M2p[o * 32 + kw] = wv;
  }
}

// popm: column-sum of Bf (bytes 0/1 -> popc per u32 = byte sum). 1 wave per o.
__global__ __launch_bounds__(64) void popm_kernel(
    const unsigned char* __restrict__ Bf, const int* __restrict__ thr1,
    int* __restrict__ carr) {
  int o = blockIdx.x;
  int t = threadIdx.x;               // t = ks*2+g
  const uint4* p = reinterpret_cast<const uint4*>(
      Bf + ((unsigned)(o >> 5) << 15) + ((unsigned)(t >> 1) << 10) +
      ((unsigned)(t & 1) << 9) + ((unsigned)(o & 31) << 4));
  uint4 v = *p;
  int s = __popc(v.x) + __popc(v.y) + __popc(v.z) + __popc(v.w);
#pragma unroll
  for (int d = 32; d >= 1; d >>= 1) s += __shfl_down(s, d);
  if (t == 0) carr[o] = thr1[o] + s - 1024;
}

// Main: block = 128 px x 1024 outs, 512 threads (8 waves), grid 512.
// R15 lessons: 1024-thr blocks get a 64-VGPR cap -> spill disaster; fused L0
// kills the ~55us pack_x1 aux cost. Here: 512 threads (cap 256 VGPR, live
// ~110), wave = 4 sequential oc32 chunks with NO inter-pass barriers.
__global__ __launch_bounds__(512) void main_kernel(
    const signed char* __restrict__ cA, const unsigned char* __restrict__ cB,
    const unsigned char* __restrict__ Bf, const int* __restrict__ carr,
    const unsigned* __restrict__ M2p, const int* __restrict__ thr2,
    const float* __restrict__ image, float* __restrict__ out) {
  __shared__ v4i Ae4[8192];          // 128 KB [chunk c=2ks+g 0..63][row 0..127]
  __shared__ unsigned lbits[4224];   // 16.5 KB [row 0..127][wd 0..31] stride 33
  __shared__ unsigned lm2[768];      //  3 KB
  __shared__ int spopx[128];
  int t = threadIdx.x;
  int lane = t & 63;
  int wv = t >> 6;                   // wave 0..7
  int n0 = blockIdx.x << 7;
  int h = n0 >> 8;                   // constant across the 128-px tile
  int w0 = n0 & 255;

  for (int r = t; r < 768; r += 512) lm2[r] = M2p[r];
  if (t < 128) spopx[t] = 0;
  __syncthreads();

  // ---- L0a: bits via ballot; thread owns features o=t and o=t+512.
  // Hand-unrolled x4: 8 independent loads in flight per iteration.
  {
    int o1 = t, o2 = t + 512;
    int av1 = (int)cA[h * 1024 + o1];
    int av2 = (int)cA[h * 1024 + o2];
    const unsigned char* cb = cB + (unsigned)w0 * 1024;
#pragma unroll 1
    for (int r4 = 0; r4 < 128; r4 += 4) {
      int v1[4], v2[4];
#pragma unroll
      for (int i = 0; i < 4; i++) {
        v1[i] = (int)cb[(unsigned)(r4 + i) * 1024 + o1];
        v2[i] = (int)cb[(unsigned)(r4 + i) * 1024 + o2];
      }
#pragma unroll
      for (int i = 0; i < 4; i++) {
        int r = r4 + i;
        unsigned long long bal1 = __ballot((av1 + v1[i]) > 0);
        unsigned long long bal2 = __ballot((av2 + v2[i]) > 0);
        if (lane == 0) {
          lbits[r * 33 + wv * 2]          = (unsigned)bal1;
          lbits[r * 33 + wv * 2 + 1]      = (unsigned)(bal1 >> 32);
          lbits[r * 33 + 16 + wv * 2]     = (unsigned)bal2;
          lbits[r * 33 + 16 + wv * 2 + 1] = (unsigned)(bal2 >> 32);
          atomicAdd(&spopx[r], __popcll(bal1) + __popcll(bal2));
        }
      }
    }
  }
  __syncthreads();

  // ---- L0b: expand bits -> i8 A-tile (lane->consecutive row: conflict-free)
  {
    int r = t & 127;
    int c0 = (t >> 7) << 4;          // 16 chunks per thread
#pragma unroll
    for (int ci = 0; ci < 16; ci++) {
      int c = c0 + ci;               // halfword index 0..63 (= 2ks+g)
      unsigned word = lbits[r * 33 + (c >> 1)];
      unsigned hwv = (c & 1) ? (word >> 16) : (word & 0xFFFFu);
      Ae4[c * 128 + r] = expand16(hwv);
    }
  }
  __syncthreads();

  // ---- L1: MFMA; wave owns oc = pass*8+wv, 4 row-tiles. xbits overlays lbits.
  unsigned* xbits = lbits;
  int g = lane >> 5;
  int col = lane & 31;

#pragma unroll 1
  for (int pass = 0; pass < 4; pass++) {
    int oc = (pass << 3) + wv;       // oc32 chunk 0..31
    const unsigned char* bp = Bf + ((unsigned)oc << 15) + (g << 9) + (col << 4);

    v16i acc0 = {0,0,0,0,0,0,0,0,0,0,0,0,0,0,0,0};
    v16i acc1 = acc0, acc2 = acc0, acc3 = acc0;

    v4i bA = *reinterpret_cast<const v4i*>(bp);
    v4i bB = *reinterpret_cast<const v4i*>(bp + 1024);
#pragma unroll 1
    for (int ks = 0; ks < 32; ks++) {
      v4i bu = bA;
      bA = bB;
      if (ks < 30) bB = *reinterpret_cast<const v4i*>(bp + (ks + 2) * 1024);
      int c = 2 * ks + g;
      v4i a0 = Ae4[c * 128 + col];
      v4i a1 = Ae4[c * 128 + 32 + col];
      v4i a2 = Ae4[c * 128 + 64 + col];
      v4i a3 = Ae4[c * 128 + 96 + col];
      acc0 = __builtin_amdgcn_mfma_i32_32x32x32_i8(a0, bu, acc0, 0, 0, 0);
      acc1 = __builtin_amdgcn_mfma_i32_32x32x32_i8(a1, bu, acc1, 0, 0, 0);
      acc2 = __builtin_amdgcn_mfma_i32_32x32x32_i8(a2, bu, acc2, 0, 0, 0);
      acc3 = __builtin_amdgcn_mfma_i32_32x32x32_i8(a3, bu, acc3, 0, 0, 0);
    }

    // threshold + ballot-pack into xbits (verified layout from R15)
    int cv = carr[(oc << 5) + col];
#pragma unroll
    for (int rt = 0; rt < 4; rt++) {
      v16i av = (rt == 0) ? acc0 : (rt == 1) ? acc1 : (rt == 2) ? acc2 : acc3;
#pragma unroll
      for (int reg = 0; reg < 16; reg++) {
        int px_lo = (rt << 5) + (reg & 3) + ((reg >> 2) << 3);
        int px = px_lo + (g << 2);
        bool bit = (2 * av[reg]) > (cv + spopx[px]);
        unsigned long long bal = __ballot(bit);
        if (lane == 0) {
          xbits[px_lo * 33 + oc]       = (unsigned)bal;
          xbits[(px_lo + 4) * 33 + oc] = (unsigned)(bal >> 32);
        }
      }
    }
  }
  __syncthreads();

  // ---- fused layer-2 + epilogue (xbits stride 33; reads staggered by px)
  int px = t >> 2, sub = t & 3;
  if (sub < 3) {
    int c = sub;
    int n = n0 + px;
    int val = 0;
#pragma unroll
    for (int b = 0; b < 8; b++) {
      int o = c * 8 + b;
      unsigned acc2s = 0;
#pragma unroll
      for (int wi = 0; wi < 32; wi++) {
        int w = (wi + px) & 31;
        acc2s += __popc(xbits[px * 33 + w] ^ lm2[o * 32 + w]);
      }
      int bit = ((int)(1024u - acc2s)) > thr2[o];
      val |= bit << (7 - b);                            // MSB-first
    }
    out[c * 65536 + n] = (float)val;
    out[196608 + c * 65536 + n] = (float)val - image[c * 65536 + n];
  }
}

extern "C" void kernel_launch(void* const* d_in, const int* in_sizes, int n_in,
                              void* d_out, int out_size, void* d_ws, size_t ws_size,
                              hipStream_t stream) {
  const float*         image = (const float*)d_in[0];
  const unsigned char* mask0 = (const unsigned char*)d_in[1];
  const int*           thr0  = (const int*)d_in[2];
  const unsigned char* mask1 = (const unsigned char*)d_in[3];
  const int*           thr1  = (const int*)d_in[4];
  const unsigned char* mask2 = (const unsigned char*)d_in[5];
  const int*           thr2  = (const int*)d_in[6];
  char* ws = (char*)d_ws;
  signed char*    cA    = (signed char*)(ws + WS_CA);
  unsigned char*  cB    = (unsigned char*)(ws + WS_CB);
  unsigned*       M2p   = (unsigned*)(ws + WS_M2P);
  int*            carr  = (int*)(ws + WS_CARR);
  unsigned char*  Bf    = (unsigned char*)(ws + WS_BF);
  float* out = (float*)d_out;

  hipLaunchKernelGGL(prep_kernel, dim3(3075), dim3(256), 0, stream,
                     mask0, thr0, mask1, mask2, cA, cB, Bf, M2p);
  hipLaunchKernelGGL(popm_kernel, dim3(1024), dim3(64), 0, stream,
                     Bf, thr1, carr);
  hipLaunchKernelGGL(main_kernel, dim3(512), dim3(512), 0, stream,
                     cA, cB, Bf, carr, M2p, thr2, image, out);
}

// Round 17
// 121.321 us; speedup vs baseline: 1.7499x; 1.2578x over previous
//
#include <hip/hip_runtime.h>
#include <stdint.h>

// 3-layer binary net. L0 fused in main. L1 = i8 MFMA with A in {0,1}, B in
// {+1,-1}: dot = 2s - popx directly, so no popx pass and threshold is a bare
// compare vs carr[o] = thr1[o] + popm[o] - 1024. L2 in a tiny separate kernel.
// ws: cA 256K | cB 256K | M2p 3KB | carr 4KB | Bf 1MB (+-1 i8, frag order) | X2p 8MB
#define WS_CA   0
#define WS_CB   262144
#define WS_M2P  524288
#define WS_CARR 527360
#define WS_BF   532480
#define WS_X2   1581056

typedef int v4i  __attribute__((ext_vector_type(4)));
typedef int v16i __attribute__((ext_vector_type(16)));

// 16 bits -> 16 i8 bytes (0/1), byte e = bit e (LSB-first)
__device__ __forceinline__ v4i expand16(unsigned h) {
  v4i a;
  a.x = (int)(__umul24(h & 15u,         0x00204081u) & 0x01010101u);
  a.y = (int)(__umul24((h >> 4) & 15u,  0x00204081u) & 0x01010101u);
  a.z = (int)(__umul24((h >> 8) & 15u,  0x00204081u) & 0x01010101u);
  a.w = (int)(__umul24((h >> 12) & 15u, 0x00204081u) & 0x01010101u);
  return a;
}

// ---- mask upload-format sniffing (bool arrays may arrive as u8, i32, or f32) ----
__device__ inline int detect_mode(const unsigned char* p) {
  unsigned nonalign = 0;
  for (int i = 0; i < 64; i++)
    if (i & 3) nonalign |= p[i];
  if (nonalign == 0) return 1;                 // int32 0/1
  bool f32ok = true;
  for (int e = 0; e < 16; e++) {
    const unsigned char* q = p + 4 * e;
    bool one  = (q[0] == 0 && q[1] == 0 && q[2] == 0x80 && q[3] == 0x3F);
    bool zero = (q[0] == 0 && q[1] == 0 && q[2] == 0 && q[3] == 0);
    if (!(one || zero)) { f32ok = false; break; }
  }
  return f32ok ? 2 : 0;
}

__device__ inline int maskbit(const unsigned char* p, int idx, int mode) {
  if (mode == 1) return ((const int*)p)[idx] & 1;
  if (mode == 2) return ((const float*)p)[idx] != 0.0f;
  return p[idx] & 1;
}

__global__ __launch_bounds__(256) void prep_kernel(
    const unsigned char* __restrict__ mask0, const int* __restrict__ thr0,
    const unsigned char* __restrict__ mask1, const unsigned char* __restrict__ mask2,
    signed char* __restrict__ cA, unsigned char* __restrict__ cB,
    unsigned char* __restrict__ Bf, unsigned* __restrict__ M2p) {
  __shared__ int smode;
  if (threadIdx.x == 0) smode = detect_mode(mask1);
  __syncthreads();
  int mode = smode;
  int gid = blockIdx.x * 256 + threadIdx.x;
  if (gid < 524288) {              // cA / cB tables for L0
    int which = gid >> 18;
    int idx = gid & 262143;
    int hw = idx >> 10;
    int o  = idx & 1023;
    int base = which ? 8 : 0;
    int cnt = 0;
#pragma unroll
    for (int i = 0; i < 8; i++) {
      int xb = (hw >> (7 - i)) & 1;                     // MSB-first bits
      int mb = maskbit(mask0, (base + i) * 1024 + o, mode);
      cnt += (xb == mb);
    }
    if (which) cB[idx] = (unsigned char)cnt;
    else       cA[idx] = (signed char)(cnt - thr0[o]);
    return;
  }
  int g1 = gid - 524288;
  if (g1 < 262144) {               // M01 -> Bf fragment layout, bytes +1/-1
    int o  = g1 & 1023;
    int kk = g1 >> 10;             // u32 chunk: feats 4kk..4kk+3
    unsigned u = 0;
#pragma unroll
    for (int j = 0; j < 4; j++)
      u |= (maskbit(mask1, (4 * kk + j) * 1024 + o, mode) ? 0x01u : 0xFFu) << (8 * j);
    unsigned off = ((unsigned)(o >> 5) << 15) + ((unsigned)(kk >> 3) << 10) +
                   ((unsigned)((kk >> 2) & 1) << 9) + ((unsigned)(o & 31) << 4) +
                   ((unsigned)(kk & 3) << 2);
    *reinterpret_cast<unsigned*>(Bf + off) = u;
    return;
  }
  int g2 = g1 - 262144;
  if (g2 < 768) {                  // pack mask2: M2p[o][kw], LSB-first
    int kw = g2 / 24, o = g2 % 24;
    unsigned wv = 0;
    for (int b = 0; b < 32; b++)
      wv |= (unsigned)maskbit(mask2, (kw * 32 + b) * 24 + o, mode) << b;
    M2p[o * 32 + kw] = wv;
  }
}

// popm from +-1 bytes: byte 0x01 has popc 1, 0xFF has 8. Over 1024 bytes:
// P = n1 + 8*(1024-n1) -> n1 = (8192 - P) / 7.   carr = thr1 + n1 - 1024.
__global__ __launch_bounds__(64) void popm_kernel(
    const unsigned char* __restrict__ Bf, const int* __restrict__ thr1,
    int* __restrict__ carr) {
  int o = blockIdx.x;
  int t = threadIdx.x;               // t = ks*2+g
  const uint4* p = reinterpret_cast<const uint4*>(
      Bf + ((unsigned)(o >> 5) << 15) + ((unsigned)(t >> 1) << 10) +
      ((unsigned)(t & 1) << 9) + ((unsigned)(o & 31) << 4));
  uint4 v = *p;
  int s = __popc(v.x) + __popc(v.y) + __popc(v.z) + __popc(v.w);
#pragma unroll
  for (int d = 32; d >= 1; d >>= 1) s += __shfl_down(s, d);
  if (t == 0) {
    int n1 = (8192 - s) / 7;
    carr[o] = thr1[o] + n1 - 1024;
  }
}

// Main: block = 64 px x 1024 outs, 512 threads (8 waves), grid 1024.
// LDS = A-i8 64KB + lbits 8.25KB = 72.3KB -> 2 blocks/CU = 4 waves/SIMD.
// Wave = 2 rt x 2 oc (acc 64 VGPR, 0.5 LDS-reads per MFMA), 2 passes.
// R15/R16 lessons: fused L0; never cap VGPR below live set; TLP is the lever.
__global__ __launch_bounds__(512) void main_kernel(
    const signed char* __restrict__ cA, const unsigned char* __restrict__ cB,
    const unsigned char* __restrict__ Bf, const int* __restrict__ carr,
    unsigned* __restrict__ X2p) {
  __shared__ v4i Ae4[4096];          // 64 KB  [c=2ks+g 0..63][row 0..63]
  __shared__ unsigned lbits[2112];   // 8.25 KB [row 0..63][wd 0..31] stride 33
  int t = threadIdx.x;
  int lane = t & 63;
  int wv = t >> 6;                   // wave 0..7
  int n0 = blockIdx.x << 6;
  int h = n0 >> 8;                   // constant across the 64-px tile
  int w0 = n0 & 255;

  // ---- L0a: bits via ballot; thread owns features o=t and o=t+512.
  {
    int o1 = t, o2 = t + 512;
    int av1 = (int)cA[h * 1024 + o1];
    int av2 = (int)cA[h * 1024 + o2];
    const unsigned char* cb = cB + (unsigned)w0 * 1024;
#pragma unroll 1
    for (int r4 = 0; r4 < 64; r4 += 4) {
      int v1[4], v2[4];
#pragma unroll
      for (int i = 0; i < 4; i++) {
        v1[i] = (int)cb[(unsigned)(r4 + i) * 1024 + o1];
        v2[i] = (int)cb[(unsigned)(r4 + i) * 1024 + o2];
      }
#pragma unroll
      for (int i = 0; i < 4; i++) {
        int r = r4 + i;
        unsigned long long bal1 = __ballot((av1 + v1[i]) > 0);
        unsigned long long bal2 = __ballot((av2 + v2[i]) > 0);
        if (lane == 0) {
          lbits[r * 33 + wv * 2]          = (unsigned)bal1;
          lbits[r * 33 + wv * 2 + 1]      = (unsigned)(bal1 >> 32);
          lbits[r * 33 + 16 + wv * 2]     = (unsigned)bal2;
          lbits[r * 33 + 16 + wv * 2 + 1] = (unsigned)(bal2 >> 32);
        }
      }
    }
  }
  __syncthreads();

  // ---- L0b: expand bits -> i8 A-tile (8 threads/row x 8 chunks; conflict-free)
  {
    int r = t & 63;
    int c0 = (t >> 6) << 3;
#pragma unroll
    for (int ci = 0; ci < 8; ci++) {
      int c = c0 + ci;               // halfword index 0..63 (= 2ks+g)
      unsigned word = lbits[r * 33 + (c >> 1)];
      unsigned hwv = (c & 1) ? (word >> 16) : (word & 0xFFFFu);
      Ae4[c * 64 + r] = expand16(hwv);
    }
  }
  __syncthreads();

  // ---- L1: MFMA; wave owns oc pair (pass*16 + wv*2, +1), rt = 2 row-tiles.
  int g = lane >> 5;
  int col = lane & 31;

#pragma unroll 1
  for (int pass = 0; pass < 2; pass++) {
    int ocp = (pass << 4) + (wv << 1);
    const unsigned char* bp0 = Bf + ((unsigned)ocp << 15) + (g << 9) + (col << 4);
    const unsigned char* bp1 = bp0 + 32768;

    v16i acc00 = {0,0,0,0,0,0,0,0,0,0,0,0,0,0,0,0};   // [rt][s]
    v16i acc10 = acc00, acc01 = acc00, acc11 = acc00;

    v4i b0n = *reinterpret_cast<const v4i*>(bp0);
    v4i b1n = *reinterpret_cast<const v4i*>(bp1);
#pragma unroll 1
    for (int ks = 0; ks < 32; ks++) {
      v4i b0 = b0n, b1 = b1n;
      if (ks < 31) {
        b0n = *reinterpret_cast<const v4i*>(bp0 + (ks + 1) * 1024);
        b1n = *reinterpret_cast<const v4i*>(bp1 + (ks + 1) * 1024);
      }
      int c = 2 * ks + g;
      v4i a0 = Ae4[c * 64 + col];
      v4i a1 = Ae4[c * 64 + 32 + col];
      acc00 = __builtin_amdgcn_mfma_i32_32x32x32_i8(a0, b0, acc00, 0, 0, 0);
      acc10 = __builtin_amdgcn_mfma_i32_32x32x32_i8(a1, b0, acc10, 0, 0, 0);
      acc01 = __builtin_amdgcn_mfma_i32_32x32x32_i8(a0, b1, acc01, 0, 0, 0);
      acc11 = __builtin_amdgcn_mfma_i32_32x32x32_i8(a1, b1, acc11, 0, 0, 0);
    }

    // threshold (av = 2s - popx, compare vs carr) + ballot-pack -> X2p
#pragma unroll
    for (int s = 0; s < 2; s++) {
      int oc = ocp + s;
      int cv = carr[(oc << 5) + col];
#pragma unroll
      for (int rt = 0; rt < 2; rt++) {
        v16i av = (s == 0) ? (rt == 0 ? acc00 : acc10)
                           : (rt == 0 ? acc01 : acc11);
#pragma unroll
        for (int reg = 0; reg < 16; reg++) {
          int px_lo = (rt << 5) + (reg & 3) + ((reg >> 2) << 3);
          bool bit = av[reg] > cv;
          unsigned long long bal = __ballot(bit);
          if (lane == 0) {
            X2p[(unsigned)(n0 + px_lo) * 32 + oc]     = (unsigned)bal;
            X2p[(unsigned)(n0 + px_lo + 4) * 32 + oc] = (unsigned)(bal >> 32);
          }
        }
      }
    }
  }
}

// Layer 2 + epilogue: 256 px/block, one px/thread.
__global__ __launch_bounds__(256) void l2_kernel(
    const uint4* __restrict__ X2p4, const unsigned* __restrict__ M2p,
    const int* __restrict__ thr2, const float* __restrict__ image,
    float* __restrict__ out) {
  __shared__ unsigned lm2[768];
  int t = threadIdx.x;
  for (int r = t; r < 768; r += 256) lm2[r] = M2p[r];
  __syncthreads();
  int n = blockIdx.x * 256 + t;
  uint4 xw[8];
#pragma unroll
  for (int q = 0; q < 8; q++) xw[q] = X2p4[(unsigned)n * 8 + q];
#pragma unroll
  for (int c = 0; c < 3; c++) {
    int val = 0;
#pragma unroll
    for (int b = 0; b < 8; b++) {
      int o = c * 8 + b;
      const unsigned* m = &lm2[o * 32];
      unsigned acc2 = 0;
#pragma unroll
      for (int q = 0; q < 8; q++) {
        acc2 += __popc(xw[q].x ^ m[q * 4 + 0]);
        acc2 += __popc(xw[q].y ^ m[q * 4 + 1]);
        acc2 += __popc(xw[q].z ^ m[q * 4 + 2]);
        acc2 += __popc(xw[q].w ^ m[q * 4 + 3]);
      }
      int bit = ((int)(1024u - acc2)) > thr2[o];
      val |= bit << (7 - b);                            // MSB-first
    }
    out[c * 65536 + n] = (float)val;
    out[196608 + c * 65536 + n] = (float)val - image[c * 65536 + n];
  }
}

extern "C" void kernel_launch(void* const* d_in, const int* in_sizes, int n_in,
                              void* d_out, int out_size, void* d_ws, size_t ws_size,
                              hipStream_t stream) {
  const float*         image = (const float*)d_in[0];
  const unsigned char* mask0 = (const unsigned char*)d_in[1];
  const int*           thr0  = (const int*)d_in[2];
  const unsigned char* mask1 = (const unsigned char*)d_in[3];
  const int*           thr1  = (const int*)d_in[4];
  const unsigned char* mask2 = (const unsigned char*)d_in[5];
  const int*           thr2  = (const int*)d_in[6];
  char* ws = (char*)d_ws;
  signed char*    cA    = (signed char*)(ws + WS_CA);
  unsigned char*  cB    = (unsigned char*)(ws + WS_CB);
  unsigned*       M2p   = (unsigned*)(ws + WS_M2P);
  int*            carr  = (int*)(ws + WS_CARR);
  unsigned char*  Bf    = (unsigned char*)(ws + WS_BF);
  unsigned*       X2p   = (unsigned*)(ws + WS_X2);
  float* out = (float*)d_out;

  hipLaunchKernelGGL(prep_kernel, dim3(3075), dim3(256), 0, stream,
                     mask0, thr0, mask1, mask2, cA, cB, Bf, M2p);
  hipLaunchKernelGGL(popm_kernel, dim3(1024), dim3(64), 0, stream,
                     Bf, thr1, carr);
  hipLaunchKernelGGL(main_kernel, dim3(1024), dim3(512), 0, stream,
                     cA, cB, Bf, carr, X2p);
  hipLaunchKernelGGL(l2_kernel, dim3(256), dim3(256), 0, stream,
                     (const uint4*)X2p, M2p, thr2, image, out);
}